// Round 17
// baseline (129.013 us; speedup 1.0000x reference)
//
#include <hip/hip_runtime.h>
#include <stdint.h>

#define B_ROWS 4096
#define D_DIM  512
#define N_TOT  8192
#define TEMP_INV 2.0f   // 1/0.5
#define NB     64       // N_TOT / 128 tiles per dim
#define NTRI   2080     // NB*(NB+1)/2
#define KT_N   (D_DIM / 32)  // 16 K-steps
// ctl layout (words): panel counters cnt[p] at p*32 (p=0..63, cacheline-padded),
// loss accumulator (float) at 2080, panels-done at 2112.
#define CTL_LOSS 2080
#define CTL_DONE 2112
#define CTL_WORDS 2144

typedef __bf16 bf16x8 __attribute__((ext_vector_type(8)));
typedef float  f32x4  __attribute__((ext_vector_type(4)));
typedef unsigned short ushort8 __attribute__((ext_vector_type(8)));

#define LGKM0()    asm volatile("s_waitcnt lgkmcnt(0)" ::: "memory")
#define BAR()      do { asm volatile("" ::: "memory"); \
                        __builtin_amdgcn_s_barrier();  \
                        asm volatile("" ::: "memory"); } while (0)

__device__ __forceinline__ unsigned short f2bf(float f) {
    union { float f; unsigned int u; } c; c.f = f;
    unsigned int u = c.u;
    return (unsigned short)((u + 0x7fffu + ((u >> 16) & 1u)) >> 16);
}

// ------- kernel 1: fused L2-normalize (write bf16 z) + positive-pair dot -------
// one wave per pair k; also zeroes rowsum and the ctl block
__global__ __launch_bounds__(256) void normpos_kernel(
    const float* __restrict__ xi, const float* __restrict__ xj,
    unsigned short* __restrict__ z, float* __restrict__ pos,
    float* __restrict__ rowsum, unsigned* __restrict__ ctl) {
    if (blockIdx.x < N_TOT / 256) rowsum[blockIdx.x * 256 + threadIdx.x] = 0.f;
    if (blockIdx.x == 0)
        for (int i = threadIdx.x; i < CTL_WORDS; i += 256) ctl[i] = 0u;
    const int wid  = threadIdx.x >> 6;
    const int lane = threadIdx.x & 63;
    const int k    = blockIdx.x * 4 + wid;
    const float4* a4 = (const float4*)(xi + (size_t)k * D_DIM);
    const float4* b4 = (const float4*)(xj + (size_t)k * D_DIM);
    float4 va0 = a4[2 * lane], va1 = a4[2 * lane + 1];
    float4 vb0 = b4[2 * lane], vb1 = b4[2 * lane + 1];
    float ssa = va0.x*va0.x + va0.y*va0.y + va0.z*va0.z + va0.w*va0.w
              + va1.x*va1.x + va1.y*va1.y + va1.z*va1.z + va1.w*va1.w;
    float ssb = vb0.x*vb0.x + vb0.y*vb0.y + vb0.z*vb0.z + vb0.w*vb0.w
              + vb1.x*vb1.x + vb1.y*vb1.y + vb1.z*vb1.z + vb1.w*vb1.w;
    float dot = va0.x*vb0.x + va0.y*vb0.y + va0.z*vb0.z + va0.w*vb0.w
              + va1.x*vb1.x + va1.y*vb1.y + va1.z*vb1.z + va1.w*vb1.w;
    #pragma unroll
    for (int m = 32; m >= 1; m >>= 1) {
        ssa += __shfl_xor(ssa, m);
        ssb += __shfl_xor(ssb, m);
        dot += __shfl_xor(dot, m);
    }
    const float rna = 1.0f / fmaxf(sqrtf(ssa), 1e-12f);
    const float rnb = 1.0f / fmaxf(sqrtf(ssb), 1e-12f);
    float av[8] = {va0.x, va0.y, va0.z, va0.w, va1.x, va1.y, va1.z, va1.w};
    float bv[8] = {vb0.x, vb0.y, vb0.z, vb0.w, vb1.x, vb1.y, vb1.z, vb1.w};
    union { ushort8 v; unsigned short s[8]; } oa, ob;
    #pragma unroll
    for (int i = 0; i < 8; ++i) {
        oa.s[i] = f2bf(av[i] * rna);
        ob.s[i] = f2bf(bv[i] * rnb);
    }
    *(ushort8*)(z + (size_t)k * D_DIM + lane * 8) = oa.v;
    *(ushort8*)(z + (size_t)(k + B_ROWS) * D_DIM + lane * 8) = ob.v;
    if (lane == 0) pos[k] = dot * rna * rnb;
}

// -------- kernel 2: v17 -- REG-STAGING A/B against gl_lds (core experiment) --------
// Cross-round invariant: the core runs at ~5000 cy per CU-resident K-iteration
// regardless of barriers/occupancy/pipeline-depth/staged-bytes (v9 vs r13).
// Last unfalsified mechanism: the vmcnt-retire path of global_load_lds itself.
// A/B: identical addresses (swizzled global source), identical LDS image (linear
// dest), identical tile/wave geometry and tail -- staging swapped to
// global_load_dwordx4 -> VGPR -> ds_write_b128. One barrier per iteration.
// Hazard audit: compute(cur) reads buf[cur] (written at iter kt-1 before its
// LGKM0+BAR). stage_write(cur^1) overwrites buf[cur^1], whose last readers were
// iter kt-1's compute (ds_reads retired by that iter's LGKM0, barrier-ordered).
// Loads for kt+2 are issued after stage_write consumes the regs; compiler
// inserts the counted vmcnt wait before the next ds_write use.
__global__ __launch_bounds__(512, 4) void simrow_kernel(
    const unsigned short* __restrict__ z, float* __restrict__ rowsum,
    const float* __restrict__ pos, float* __restrict__ out,
    unsigned* __restrict__ ctl) {
    __shared__ unsigned short As[2][128 * 32];  // 2 x 8 KB
    __shared__ unsigned short Bs[2][128 * 32];  // 2 x 8 KB
    __shared__ float rsum[128];
    __shared__ float csum[128];
    __shared__ float pw[8];
    __shared__ int f1s, f2s, lastf;
    const int tid  = threadIdx.x;
    const int lane = tid & 63;
    const int wid  = tid >> 6;   // 0..7

    // map linear block id -> upper-triangular (bi, bj), bi <= bj
    const int t0 = blockIdx.x;
    int bi = (int)(NB + 0.5f - sqrtf((NB + 0.5f) * (NB + 0.5f) - 2.0f * t0));
    if (bi < 0) bi = 0;
    if (bi > NB - 1) bi = NB - 1;
    while (bi > 0 && (bi * NB - bi * (bi - 1) / 2) > t0) --bi;
    while ((bi + 1) * NB - (bi + 1) * bi / 2 <= t0) ++bi;
    const int bj = bi + (t0 - (bi * NB - bi * (bi - 1) / 2));
    const int row0 = bi * 128;
    const int col0 = bj * 128;
    const bool diag = (bi == bj);

    if (tid < 128) { rsum[tid] = 0.f; csum[tid] = 0.f; }

    const int wr = wid >> 2;    // 0..1 : 64-row band
    const int wc = wid & 3;     // 0..3 : 32-col band
    f32x4 acc[4][2] = {};

    // staging: wave wid covers rows [wid*16, wid*16+16) of the 128x32 tile.
    // Same swizzled global addresses as the gl_lds version; LDS dest linear at
    // (wid*16)*32 + lane*8 ushorts (byte-identical LDS image).
    const int srow = wid * 16 + (lane >> 2);
    const int skc  = ((lane & 3) ^ ((lane >> 3) & 3)) * 8;
    const unsigned short* gA = z + (size_t)(row0 + srow) * D_DIM + skc;
    const unsigned short* gB = z + (size_t)(col0 + srow) * D_DIM + skc;
    const int wbase = (wid * 16) * 32 + lane * 8;

    const int kqi = lane >> 4;         // desired global k-chunk
    const int ml  = lane & 15;
    const int sw  = (ml >> 1) & 3;     // swizzle term for this row parity
    const int slot = (kqi ^ sw) * 8;

    bf16x8 ra, rb;
    auto stage_load = [&](int kt) {
        ra = *(const bf16x8*)(gA + kt * 32);
        rb = *(const bf16x8*)(gB + kt * 32);
    };
    auto stage_write = [&](int buf) {
        *(bf16x8*)&As[buf][wbase] = ra;   // compiler auto-waits vmcnt for ra
        *(bf16x8*)&Bs[buf][wbase] = rb;
    };
    auto compute = [&](int buf) {
        bf16x8 af[4], bfr[2];
        #pragma unroll
        for (int mi = 0; mi < 4; ++mi)
            af[mi] = *(const bf16x8*)&As[buf][(wr * 64 + mi * 16 + ml) * 32 + slot];
        #pragma unroll
        for (int ni = 0; ni < 2; ++ni)
            bfr[ni] = *(const bf16x8*)&Bs[buf][(wc * 32 + ni * 16 + ml) * 32 + slot];
        #pragma unroll
        for (int mi = 0; mi < 4; ++mi)
            #pragma unroll
            for (int ni = 0; ni < 2; ++ni)
                acc[mi][ni] = __builtin_amdgcn_mfma_f32_16x16x32_bf16(
                    af[mi], bfr[ni], acc[mi][ni], 0, 0, 0);
    };

    // prologue: tile 0 -> regs -> buf0; issue tile 1 loads; publish buf0
    stage_load(0);
    stage_write(0);
    stage_load(1);
    LGKM0();
    BAR();

    for (int kt = 0; kt < KT_N; ++kt) {
        const int cur = kt & 1;
        compute(cur);
        if (kt + 1 < KT_N) stage_write(cur ^ 1);   // regs hold tile kt+1
        if (kt + 2 < KT_N) stage_load(kt + 2);     // full iteration of flight
        LGKM0();      // my ds_reads + ds_writes retired
        BAR();        // all waves: buf[cur^1] published, buf[cur] free
    }

    // epilogue: e = exp(2*sim), mask diagonal; row sums always, col sums if off-diag
    const int quad = lane >> 4;
    const int cl   = lane & 15;
    float colacc[2] = {0.f, 0.f};
    #pragma unroll
    for (int mi = 0; mi < 4; ++mi) {
        #pragma unroll
        for (int r = 0; r < 4; ++r) {
            const int lrow = wr * 64 + mi * 16 + quad * 4 + r;
            const int irow = row0 + lrow;
            float s = 0.f;
            #pragma unroll
            for (int ni = 0; ni < 2; ++ni) {
                const int jcol = col0 + wc * 32 + ni * 16 + cl;
                float e = __expf(TEMP_INV * acc[mi][ni][r]);
                e = (irow == jcol) ? 0.f : e;
                s += e;
                colacc[ni] += e;
            }
            s += __shfl_xor(s, 1);
            s += __shfl_xor(s, 2);
            s += __shfl_xor(s, 4);
            s += __shfl_xor(s, 8);
            if (cl == 0) atomicAdd(&rsum[lrow], s);
        }
    }
    if (!diag) {
        #pragma unroll
        for (int ni = 0; ni < 2; ++ni) {
            float c = colacc[ni];
            c += __shfl_xor(c, 16);
            c += __shfl_xor(c, 32);
            if (quad == 0) atomicAdd(&csum[wc * 32 + ni * 16 + cl], c);
        }
    }
    __syncthreads();
    if (tid < 128) {
        atomicAdd(&rowsum[row0 + tid], rsum[tid]);
        if (!diag) atomicAdd(&rowsum[col0 + tid], csum[tid]);
    }

    // ---- panel-distributed fence-free finalize (v16, unchanged) ----
    __syncthreads();
    if (tid == 0) {
        unsigned o1 = __hip_atomic_fetch_add(&ctl[bi * 32], 1u, __ATOMIC_RELAXED,
                                             __HIP_MEMORY_SCOPE_AGENT);
        f1s = (o1 == NB - 1);
        f2s = 0;
        if (!diag) {
            unsigned o2 = __hip_atomic_fetch_add(&ctl[bj * 32], 1u,
                                                 __ATOMIC_RELAXED,
                                                 __HIP_MEMORY_SCOPE_AGENT);
            f2s = (o2 == NB - 1);
        }
    }
    __syncthreads();

    auto finish_panel = [&](int p) {
        float part = 0.f;
        if (tid < 128)
            part = logf(atomicAdd(&rowsum[p * 128 + tid], 0.0f));  // coherent RMW
        #pragma unroll
        for (int m = 32; m >= 1; m >>= 1) part += __shfl_xor(part, m);
        if (lane == 0) pw[wid] = part;
        __syncthreads();
        if (tid == 0) {
            float tot = pw[0] + pw[1] + pw[2] + pw[3]
                      + pw[4] + pw[5] + pw[6] + pw[7];
            atomicAdd((float*)&ctl[CTL_LOSS], tot);   // device-scope float add
        }
        __syncthreads();   // drains vmcnt -> lossacc add complete before done++
        if (tid == 0) {
            unsigned d = __hip_atomic_fetch_add(&ctl[CTL_DONE], 1u,
                                                __ATOMIC_RELAXED,
                                                __HIP_MEMORY_SCOPE_AGENT);
            lastf = (d == NB - 1);
        }
        __syncthreads();
        if (lastf) {
            float ps = 0.f;
            for (int i = tid; i < B_ROWS; i += 512) ps += pos[i];
            #pragma unroll
            for (int m = 32; m >= 1; m >>= 1) ps += __shfl_xor(ps, m);
            if (lane == 0) pw[wid] = ps;
            __syncthreads();
            if (tid == 0) {
                float ptot = pw[0] + pw[1] + pw[2] + pw[3]
                           + pw[4] + pw[5] + pw[6] + pw[7];
                float ltot = atomicAdd((float*)&ctl[CTL_LOSS], 0.0f);
                // loss = mean(log denom) - (2*posSum)/(temp*N)
                out[0] = ltot / (float)N_TOT
                       - ptot * (2.0f * TEMP_INV / (float)N_TOT);
            }
        }
        __syncthreads();
    };

    if (f1s) finish_panel(bi);
    if (f2s) finish_panel(bj);
}

extern "C" void kernel_launch(void* const* d_in, const int* in_sizes, int n_in,
                              void* d_out, int out_size, void* d_ws, size_t ws_size,
                              hipStream_t stream) {
    const float* xi = (const float*)d_in[0];
    const float* xj = (const float*)d_in[1];
    float* out = (float*)d_out;
    char* ws = (char*)d_ws;

    unsigned short* z = (unsigned short*)ws;                       // 8 MB bf16
    float* rowsum = (float*)(ws + (size_t)N_TOT * D_DIM * 2);      // 32 KB
    float* pos = rowsum + N_TOT;                                   // 16 KB
    unsigned* ctl = (unsigned*)(pos + B_ROWS);                     // 8.6 KB

    normpos_kernel<<<B_ROWS / 4, 256, 0, stream>>>(xi, xj, z, pos, rowsum, ctl);
    simrow_kernel<<<NTRI, 512, 0, stream>>>(z, rowsum, pos, out, ctl);
}

// Round 18
// 126.814 us; speedup vs baseline: 1.0173x; 1.0173x over previous
//
#include <hip/hip_runtime.h>
#include <stdint.h>

#define B_ROWS 4096
#define D_DIM  512
#define N_TOT  8192
#define TEMP_INV 2.0f   // 1/0.5
#define NB     64       // N_TOT / 128 tiles per dim
#define NTRI   2080     // NB*(NB+1)/2
#define KT_N   (D_DIM / 32)  // 16 K-steps
// ctl layout (words): panel counters cnt[p] at p*32 (p=0..63, cacheline-padded),
// loss accumulator (float) at 2080, panels-done at 2112.
#define CTL_LOSS 2080
#define CTL_DONE 2112
#define CTL_WORDS 2144

typedef __bf16 bf16x8 __attribute__((ext_vector_type(8)));
typedef float  f32x4  __attribute__((ext_vector_type(4)));
typedef unsigned short ushort8 __attribute__((ext_vector_type(8)));

#define VM_WAIT(N) asm volatile("s_waitcnt vmcnt(" #N ")" ::: "memory")
#define LGKM0()    asm volatile("s_waitcnt lgkmcnt(0)" ::: "memory")
#define BAR()      do { asm volatile("" ::: "memory"); \
                        __builtin_amdgcn_s_barrier();  \
                        asm volatile("" ::: "memory"); } while (0)

__device__ __forceinline__ unsigned short f2bf(float f) {
    union { float f; unsigned int u; } c; c.f = f;
    unsigned int u = c.u;
    return (unsigned short)((u + 0x7fffu + ((u >> 16) & 1u)) >> 16);
}

// async global->LDS, 16B per lane. LDS dest is wave-uniform base + lane*16;
// global source is per-lane (carries the swizzle).
__device__ __forceinline__ void gl_lds16(const void* g, void* l) {
    __builtin_amdgcn_global_load_lds(
        (__attribute__((address_space(1))) void*)(uintptr_t)g,
        (__attribute__((address_space(3))) void*)(uintptr_t)l,
        16, 0, 0);
}

// ------- kernel 1: fused L2-normalize (write bf16 z) + positive-pair dot -------
// one wave per pair k; also zeroes rowsum and the ctl block
__global__ __launch_bounds__(256) void normpos_kernel(
    const float* __restrict__ xi, const float* __restrict__ xj,
    unsigned short* __restrict__ z, float* __restrict__ pos,
    float* __restrict__ rowsum, unsigned* __restrict__ ctl) {
    if (blockIdx.x < N_TOT / 256) rowsum[blockIdx.x * 256 + threadIdx.x] = 0.f;
    if (blockIdx.x == 0)
        for (int i = threadIdx.x; i < CTL_WORDS; i += 256) ctl[i] = 0u;
    const int wid  = threadIdx.x >> 6;
    const int lane = threadIdx.x & 63;
    const int k    = blockIdx.x * 4 + wid;
    const float4* a4 = (const float4*)(xi + (size_t)k * D_DIM);
    const float4* b4 = (const float4*)(xj + (size_t)k * D_DIM);
    float4 va0 = a4[2 * lane], va1 = a4[2 * lane + 1];
    float4 vb0 = b4[2 * lane], vb1 = b4[2 * lane + 1];
    float ssa = va0.x*va0.x + va0.y*va0.y + va0.z*va0.z + va0.w*va0.w
              + va1.x*va1.x + va1.y*va1.y + va1.z*va1.z + va1.w*va1.w;
    float ssb = vb0.x*vb0.x + vb0.y*vb0.y + vb0.z*vb0.z + vb0.w*vb0.w
              + vb1.x*vb1.x + vb1.y*vb1.y + vb1.z*vb1.z + vb1.w*vb1.w;
    float dot = va0.x*vb0.x + va0.y*vb0.y + va0.z*vb0.z + va0.w*vb0.w
              + va1.x*vb1.x + va1.y*vb1.y + va1.z*vb1.z + va1.w*vb1.w;
    #pragma unroll
    for (int m = 32; m >= 1; m >>= 1) {
        ssa += __shfl_xor(ssa, m);
        ssb += __shfl_xor(ssb, m);
        dot += __shfl_xor(dot, m);
    }
    const float rna = 1.0f / fmaxf(sqrtf(ssa), 1e-12f);
    const float rnb = 1.0f / fmaxf(sqrtf(ssb), 1e-12f);
    float av[8] = {va0.x, va0.y, va0.z, va0.w, va1.x, va1.y, va1.z, va1.w};
    float bv[8] = {vb0.x, vb0.y, vb0.z, vb0.w, vb1.x, vb1.y, vb1.z, vb1.w};
    union { ushort8 v; unsigned short s[8]; } oa, ob;
    #pragma unroll
    for (int i = 0; i < 8; ++i) {
        oa.s[i] = f2bf(av[i] * rna);
        ob.s[i] = f2bf(bv[i] * rnb);
    }
    *(ushort8*)(z + (size_t)k * D_DIM + lane * 8) = oa.v;
    *(ushort8*)(z + (size_t)(k + B_ROWS) * D_DIM + lane * 8) = ob.v;
    if (lane == 0) pos[k] = dot * rna * rnb;
}

// -------- kernel 2: champion simrow + PANEL-DISTRIBUTED fence-free finalize --------
// Final configuration (session best, 126.7us total):
//   - 8-wave 128x128 tile, acc[4][2]=32 AGPR, VGPR 40 -> ~47% occupancy
//   - 3-deep LDS pipeline, counted VM_WAIT(4) across raw barriers (tiles t+1,t+2
//     in flight); diag blocks stage B redundantly (identical addresses) for
//     uniform vmcnt arithmetic
//   - proven 0-conflict XOR k-chunk swizzle on stage-source and read sides
//   - fence-free finalize: panel p's rowsum is final when cnt[p]==64 (each
//     increment preceded by a vmcnt-drained __syncthreads, so the atomics are
//     complete at the coherence point); the finishing block computes that
//     panel's log-sum in the tail shadow; the 64th finisher adds the pos term.
__global__ __launch_bounds__(512, 4) void simrow_kernel(
    const unsigned short* __restrict__ z, float* __restrict__ rowsum,
    const float* __restrict__ pos, float* __restrict__ out,
    unsigned* __restrict__ ctl) {
    __shared__ unsigned short As[3][128 * 32];  // 3 x 8 KB
    __shared__ unsigned short Bs[3][128 * 32];  // 3 x 8 KB
    __shared__ float rsum[128];
    __shared__ float csum[128];
    __shared__ float pw[8];
    __shared__ int f1s, f2s, lastf;
    const int tid  = threadIdx.x;
    const int lane = tid & 63;
    const int wid  = tid >> 6;   // 0..7

    // map linear block id -> upper-triangular (bi, bj), bi <= bj
    const int t0 = blockIdx.x;
    int bi = (int)(NB + 0.5f - sqrtf((NB + 0.5f) * (NB + 0.5f) - 2.0f * t0));
    if (bi < 0) bi = 0;
    if (bi > NB - 1) bi = NB - 1;
    while (bi > 0 && (bi * NB - bi * (bi - 1) / 2) > t0) --bi;
    while ((bi + 1) * NB - (bi + 1) * bi / 2 <= t0) ++bi;
    const int bj = bi + (t0 - (bi * NB - bi * (bi - 1) / 2));
    const int row0 = bi * 128;
    const int col0 = bj * 128;
    const bool diag = (bi == bj);

    if (tid < 128) { rsum[tid] = 0.f; csum[tid] = 0.f; }

    const int wr = wid >> 2;    // 0..1 : 64-row band
    const int wc = wid & 3;     // 0..3 : 32-col band
    f32x4 acc[4][2] = {};

    // staging: wave wid covers rows [wid*16, wid*16+16) of the 128x32 tile.
    const int srow = wid * 16 + (lane >> 2);
    const int skc  = ((lane & 3) ^ ((lane >> 3) & 3)) * 8;
    const unsigned short* gA = z + (size_t)(row0 + srow) * D_DIM + skc;
    const unsigned short* gB = z + (size_t)(col0 + srow) * D_DIM + skc;

    const int kqi = lane >> 4;         // desired global k-chunk
    const int ml  = lane & 15;
    const int sw  = (ml >> 1) & 3;     // swizzle term for this row parity
    const int slot = (kqi ^ sw) * 8;

    auto stage = [&](int buf, int kt) {
        const int k0 = kt * 32;
        gl_lds16(gA + k0, &As[buf][(wid * 16) * 32]);
        gl_lds16(gB + k0, &Bs[buf][(wid * 16) * 32]);
    };
    auto compute = [&](int buf) {
        bf16x8 af[4], bfr[2];
        #pragma unroll
        for (int mi = 0; mi < 4; ++mi)
            af[mi] = *(const bf16x8*)&As[buf][(wr * 64 + mi * 16 + ml) * 32 + slot];
        #pragma unroll
        for (int ni = 0; ni < 2; ++ni)
            bfr[ni] = *(const bf16x8*)&Bs[buf][(wc * 32 + ni * 16 + ml) * 32 + slot];
        #pragma unroll
        for (int mi = 0; mi < 4; ++mi)
            #pragma unroll
            for (int ni = 0; ni < 2; ++ni)
                acc[mi][ni] = __builtin_amdgcn_mfma_f32_16x16x32_bf16(
                    af[mi], bfr[ni], acc[mi][ni], 0, 0, 0);
    };

    // prologue: three tiles in flight
    stage(0, 0); stage(1, 1); stage(2, 2);

    for (int kt = 0; kt < KT_N - 2; ++kt) {
        VM_WAIT(4);          // tile kt landed; kt+1, kt+2 still flying
        BAR();
        compute(kt % 3);
        LGKM0();             // all ds_reads of buf kt%3 retired
        BAR();
        if (kt + 3 < KT_N) stage(kt % 3, kt + 3);
    }
    {   // kt = KT_N-2: only tile KT_N-1 still flying (2 ops)
        VM_WAIT(2);
        BAR();
        compute((KT_N - 2) % 3);
        LGKM0();
        BAR();
    }
    {   // kt = KT_N-1: drain
        VM_WAIT(0);
        BAR();
        compute((KT_N - 1) % 3);
    }

    // epilogue: e = exp(2*sim), mask diagonal; row sums always, col sums if off-diag
    const int quad = lane >> 4;
    const int cl   = lane & 15;
    float colacc[2] = {0.f, 0.f};
    #pragma unroll
    for (int mi = 0; mi < 4; ++mi) {
        #pragma unroll
        for (int r = 0; r < 4; ++r) {
            const int lrow = wr * 64 + mi * 16 + quad * 4 + r;
            const int irow = row0 + lrow;
            float s = 0.f;
            #pragma unroll
            for (int ni = 0; ni < 2; ++ni) {
                const int jcol = col0 + wc * 32 + ni * 16 + cl;
                float e = __expf(TEMP_INV * acc[mi][ni][r]);
                e = (irow == jcol) ? 0.f : e;
                s += e;
                colacc[ni] += e;
            }
            s += __shfl_xor(s, 1);
            s += __shfl_xor(s, 2);
            s += __shfl_xor(s, 4);
            s += __shfl_xor(s, 8);
            if (cl == 0) atomicAdd(&rsum[lrow], s);
        }
    }
    if (!diag) {
        #pragma unroll
        for (int ni = 0; ni < 2; ++ni) {
            float c = colacc[ni];
            c += __shfl_xor(c, 16);
            c += __shfl_xor(c, 32);
            if (quad == 0) atomicAdd(&csum[wc * 32 + ni * 16 + cl], c);
        }
    }
    __syncthreads();
    if (tid < 128) {
        atomicAdd(&rowsum[row0 + tid], rsum[tid]);
        if (!diag) atomicAdd(&rowsum[col0 + tid], csum[tid]);
    }

    // ---- panel-distributed fence-free finalize ----
    // __syncthreads drains vmcnt(0): this block's rowsum atomics are complete at
    // the coherence point before the panel-counter increments.
    __syncthreads();
    if (tid == 0) {
        unsigned o1 = __hip_atomic_fetch_add(&ctl[bi * 32], 1u, __ATOMIC_RELAXED,
                                             __HIP_MEMORY_SCOPE_AGENT);
        f1s = (o1 == NB - 1);
        f2s = 0;
        if (!diag) {
            unsigned o2 = __hip_atomic_fetch_add(&ctl[bj * 32], 1u,
                                                 __ATOMIC_RELAXED,
                                                 __HIP_MEMORY_SCOPE_AGENT);
            f2s = (o2 == NB - 1);
        }
    }
    __syncthreads();

    auto finish_panel = [&](int p) {
        // panel p final: compute sum(log(rowsum[128p .. 128p+128))) and add to
        // the loss accumulator; 64th finisher adds pos term and writes out.
        float part = 0.f;
        if (tid < 128)
            part = logf(atomicAdd(&rowsum[p * 128 + tid], 0.0f));  // coherent RMW
        #pragma unroll
        for (int m = 32; m >= 1; m >>= 1) part += __shfl_xor(part, m);
        if (lane == 0) pw[wid] = part;
        __syncthreads();
        if (tid == 0) {
            float tot = pw[0] + pw[1] + pw[2] + pw[3]
                      + pw[4] + pw[5] + pw[6] + pw[7];
            atomicAdd((float*)&ctl[CTL_LOSS], tot);   // device-scope float add
        }
        __syncthreads();   // drains vmcnt -> lossacc add complete before done++
        if (tid == 0) {
            unsigned d = __hip_atomic_fetch_add(&ctl[CTL_DONE], 1u,
                                                __ATOMIC_RELAXED,
                                                __HIP_MEMORY_SCOPE_AGENT);
            lastf = (d == NB - 1);
        }
        __syncthreads();
        if (lastf) {
            float ps = 0.f;
            for (int i = tid; i < B_ROWS; i += 512) ps += pos[i];
            #pragma unroll
            for (int m = 32; m >= 1; m >>= 1) ps += __shfl_xor(ps, m);
            if (lane == 0) pw[wid] = ps;
            __syncthreads();
            if (tid == 0) {
                float ptot = pw[0] + pw[1] + pw[2] + pw[3]
                           + pw[4] + pw[5] + pw[6] + pw[7];
                float ltot = atomicAdd((float*)&ctl[CTL_LOSS], 0.0f);
                // loss = mean(log denom) - (2*posSum)/(temp*N)
                out[0] = ltot / (float)N_TOT
                       - ptot * (2.0f * TEMP_INV / (float)N_TOT);
            }
        }
        __syncthreads();
    };

    if (f1s) finish_panel(bi);
    if (f2s) finish_panel(bj);
}

extern "C" void kernel_launch(void* const* d_in, const int* in_sizes, int n_in,
                              void* d_out, int out_size, void* d_ws, size_t ws_size,
                              hipStream_t stream) {
    const float* xi = (const float*)d_in[0];
    const float* xj = (const float*)d_in[1];
    float* out = (float*)d_out;
    char* ws = (char*)d_ws;

    unsigned short* z = (unsigned short*)ws;                       // 8 MB bf16
    float* rowsum = (float*)(ws + (size_t)N_TOT * D_DIM * 2);      // 32 KB
    float* pos = rowsum + N_TOT;                                   // 16 KB
    unsigned* ctl = (unsigned*)(pos + B_ROWS);                     // 8.6 KB

    normpos_kernel<<<B_ROWS / 4, 256, 0, stream>>>(xi, xj, z, pos, rowsum, ctl);
    simrow_kernel<<<NTRI, 512, 0, stream>>>(z, rowsum, pos, out, ctl);
}

// Round 19
// 122.390 us; speedup vs baseline: 1.0541x; 1.0361x over previous
//
#include <hip/hip_runtime.h>
#include <stdint.h>

#define B_ROWS 4096
#define D_DIM  512
#define N_TOT  8192
#define TEMP_INV 2.0f   // 1/0.5
#define NBI    64       // 128-row bands
#define NBJ    32       // 256-col bands
#define NT     1056     // tiles: sum_{bi}(32 - (bi>>1)) = 32 groups x 33
#define KT_N   (D_DIM / 32)  // 16 K-steps
// ctl: group counters at g*32 (g<32, cacheline-padded), loss f32 at 2080,
// done at 2112. Groups of exactly 33 (NT/32).
#define NGRP   32
#define GRP_SZ 33
#define CTL_LOSS 2080
#define CTL_DONE 2112
#define CTL_WORDS 2144

typedef __bf16 bf16x8 __attribute__((ext_vector_type(8)));
typedef float  f32x4  __attribute__((ext_vector_type(4)));
typedef unsigned short ushort8 __attribute__((ext_vector_type(8)));

#define VM_WAIT(N) asm volatile("s_waitcnt vmcnt(" #N ")" ::: "memory")
#define LGKM0()    asm volatile("s_waitcnt lgkmcnt(0)" ::: "memory")
#define BAR()      do { asm volatile("" ::: "memory"); \
                        __builtin_amdgcn_s_barrier();  \
                        asm volatile("" ::: "memory"); } while (0)

__device__ __forceinline__ unsigned short f2bf(float f) {
    union { float f; unsigned int u; } c; c.f = f;
    unsigned int u = c.u;
    return (unsigned short)((u + 0x7fffu + ((u >> 16) & 1u)) >> 16);
}

__device__ __forceinline__ void gl_lds16(const void* g, void* l) {
    __builtin_amdgcn_global_load_lds(
        (__attribute__((address_space(1))) void*)(uintptr_t)g,
        (__attribute__((address_space(3))) void*)(uintptr_t)l,
        16, 0, 0);
}

// ------- kernel 1: fused L2-normalize (write bf16 z) + positive-pair dot -------
__global__ __launch_bounds__(256) void normpos_kernel(
    const float* __restrict__ xi, const float* __restrict__ xj,
    unsigned short* __restrict__ z, float* __restrict__ pos,
    float* __restrict__ rowsum, unsigned* __restrict__ ctl) {
    if (blockIdx.x < N_TOT / 256) rowsum[blockIdx.x * 256 + threadIdx.x] = 0.f;
    if (blockIdx.x == 0)
        for (int i = threadIdx.x; i < CTL_WORDS; i += 256) ctl[i] = 0u;
    const int wid  = threadIdx.x >> 6;
    const int lane = threadIdx.x & 63;
    const int k    = blockIdx.x * 4 + wid;
    const float4* a4 = (const float4*)(xi + (size_t)k * D_DIM);
    const float4* b4 = (const float4*)(xj + (size_t)k * D_DIM);
    float4 va0 = a4[2 * lane], va1 = a4[2 * lane + 1];
    float4 vb0 = b4[2 * lane], vb1 = b4[2 * lane + 1];
    float ssa = va0.x*va0.x + va0.y*va0.y + va0.z*va0.z + va0.w*va0.w
              + va1.x*va1.x + va1.y*va1.y + va1.z*va1.z + va1.w*va1.w;
    float ssb = vb0.x*vb0.x + vb0.y*vb0.y + vb0.z*vb0.z + vb0.w*vb0.w
              + vb1.x*vb1.x + vb1.y*vb1.y + vb1.z*vb1.z + vb1.w*vb1.w;
    float dot = va0.x*vb0.x + va0.y*vb0.y + va0.z*vb0.z + va0.w*vb0.w
              + va1.x*vb1.x + va1.y*vb1.y + va1.z*vb1.z + va1.w*vb1.w;
    #pragma unroll
    for (int m = 32; m >= 1; m >>= 1) {
        ssa += __shfl_xor(ssa, m);
        ssb += __shfl_xor(ssb, m);
        dot += __shfl_xor(dot, m);
    }
    const float rna = 1.0f / fmaxf(sqrtf(ssa), 1e-12f);
    const float rnb = 1.0f / fmaxf(sqrtf(ssb), 1e-12f);
    float av[8] = {va0.x, va0.y, va0.z, va0.w, va1.x, va1.y, va1.z, va1.w};
    float bv[8] = {vb0.x, vb0.y, vb0.z, vb0.w, vb1.x, vb1.y, vb1.z, vb1.w};
    union { ushort8 v; unsigned short s[8]; } oa, ob;
    #pragma unroll
    for (int i = 0; i < 8; ++i) {
        oa.s[i] = f2bf(av[i] * rna);
        ob.s[i] = f2bf(bv[i] * rnb);
    }
    *(ushort8*)(z + (size_t)k * D_DIM + lane * 8) = oa.v;
    *(ushort8*)(z + (size_t)(k + B_ROWS) * D_DIM + lane * 8) = ob.v;
    if (lane == 0) pos[k] = dot * rna * rnb;
}

// -------- kernel 2: v19 -- 128x256 asymmetric tile (max FLOP per ds_read byte) --
// Model (r18 ledger): per-block-iter wall time = ds_read bytes / ~21 B/cy,
// invariant across occupancy/pipeline/tile (v9: 48KB->0.97us; r13: 96KB->1.9us).
// Lever: fragment reuse. 8 waves x 64x64 output (acc[4][4]): 2048 FLOP/B vs
// v9's 1365. Total ds_read 1.6GB->1.08GB; iter-slots/CU 65->33; 2 blocks/CU
// kept (~112 unified regs <= 128 bracket, 73.6KB LDS). Proven 3-deep
// counted-vmcnt skeleton; stage = 3 gl_lds/wave (A + B-low + B-high) ->
// VM_WAIT(6) steady, (3)/(0) tail. Triangle: tiles (bi,bj), bi<64 (128-row),
// bj<32 (256-col), kept iff bj >= bi>>1 (NT=1056). Straddle tiles masked
// uniformly (jcol<=irow -> 0); every tile adds row-sums AND col-sums
// (strict-upper e_ij to row i and col j covers both triangles exactly).
// Tail: v15 fence-free tree, groups t0&31 of exactly 33.
__global__ __launch_bounds__(512, 4) void simrow_kernel(
    const unsigned short* __restrict__ z, float* __restrict__ rowsum,
    const float* __restrict__ pos, float* __restrict__ out,
    unsigned* __restrict__ ctl) {
    __shared__ unsigned short As[3][128 * 32];  // 3 x 8 KB
    __shared__ unsigned short Bs[3][256 * 32];  // 3 x 16 KB
    __shared__ float rsum[128];
    __shared__ float csum[256];
    __shared__ float pw[8];
    __shared__ int lastf;
    const int tid  = threadIdx.x;
    const int lane = tid & 63;
    const int wid  = tid >> 6;   // 0..7

    // t0 -> (bi, bj): start(bi) = 32*bi - f(bi), f(b)=h*(h-1)+(b&1)*h, h=b>>1
    const int t0 = blockIdx.x;
    auto startf = [](int b) {
        int h = b >> 1;
        return 32 * b - (h * (h - 1) + (b & 1) * h);
    };
    int bi = t0 / 17; if (bi > NBI - 1) bi = NBI - 1;
    while (bi > 0 && startf(bi) > t0) --bi;
    while (bi < NBI - 1 && startf(bi + 1) <= t0) ++bi;
    const int bj = (bi >> 1) + (t0 - startf(bi));
    const int row0 = bi * 128;
    const int col0 = bj * 256;

    if (tid < 128) rsum[tid] = 0.f;
    if (tid < 256) csum[tid] = 0.f;

    const int wr = wid >> 2;    // 0..1 : 64-row band of A
    const int wc = wid & 3;     // 0..3 : 64-col band of B
    f32x4 acc[4][4] = {};

    // staging: A 128x32 -- wave wid rows [wid*16,+16), 1 gl_lds;
    //          B 256x32 -- wave wid rows [wid*32,+32), 2 gl_lds (16 rows each).
    // lane -> row-in-16 = lane>>2, chunk = lane&3; source chunk ^= (lane>>3)&3
    // ((row>>1)&3 == (lane>>3)&3 since all row bases are multiples of 16).
    const int r16 = lane >> 2;
    const int skc = ((lane & 3) ^ ((lane >> 3) & 3)) * 8;
    const unsigned short* gA  = z + (size_t)(row0 + wid * 16 + r16)      * D_DIM + skc;
    const unsigned short* gB0 = z + (size_t)(col0 + wid * 32 + r16)      * D_DIM + skc;
    const unsigned short* gB1 = z + (size_t)(col0 + wid * 32 + 16 + r16) * D_DIM + skc;

    const int kqi = lane >> 4;         // desired global k-chunk
    const int ml  = lane & 15;
    const int sw  = (ml >> 1) & 3;     // swizzle term for this row parity
    const int slot = (kqi ^ sw) * 8;

    auto stage = [&](int buf, int kt) {   // exactly 3 VMEM ops per wave
        const int k0 = kt * 32;
        gl_lds16(gA  + k0, &As[buf][(wid * 16) * 32]);
        gl_lds16(gB0 + k0, &Bs[buf][(wid * 32) * 32]);
        gl_lds16(gB1 + k0, &Bs[buf][(wid * 32 + 16) * 32]);
    };
    auto compute = [&](int buf) {
        bf16x8 af[4], bfr[4];
        #pragma unroll
        for (int mi = 0; mi < 4; ++mi)
            af[mi] = *(const bf16x8*)&As[buf][(wr * 64 + mi * 16 + ml) * 32 + slot];
        #pragma unroll
        for (int ni = 0; ni < 4; ++ni)
            bfr[ni] = *(const bf16x8*)&Bs[buf][(wc * 64 + ni * 16 + ml) * 32 + slot];
        #pragma unroll
        for (int mi = 0; mi < 4; ++mi)
            #pragma unroll
            for (int ni = 0; ni < 4; ++ni)
                acc[mi][ni] = __builtin_amdgcn_mfma_f32_16x16x32_bf16(
                    af[mi], bfr[ni], acc[mi][ni], 0, 0, 0);
    };

    // prologue: three tiles in flight (9 VMEM/wave outstanding)
    stage(0, 0); stage(1, 1); stage(2, 2);

    for (int kt = 0; kt < KT_N - 2; ++kt) {
        VM_WAIT(6);          // tile kt landed; kt+1, kt+2 still flying
        BAR();
        compute(kt % 3);
        LGKM0();             // all ds_reads of buf kt%3 retired
        BAR();
        if (kt + 3 < KT_N) stage(kt % 3, kt + 3);
    }
    {   // kt = KT_N-2: only tile KT_N-1 still flying (3 ops)
        VM_WAIT(3);
        BAR();
        compute((KT_N - 2) % 3);
        LGKM0();
        BAR();
    }
    {   // kt = KT_N-1: drain
        VM_WAIT(0);
        BAR();
        compute((KT_N - 1) % 3);
    }

    // epilogue: e = exp(2*sim); STRICT-UPPER mask (jcol <= irow -> 0);
    // rows AND cols always (symmetry covers the lower triangle).
    const int quad = lane >> 4;
    const int cl   = lane & 15;
    float colacc[4] = {0.f, 0.f, 0.f, 0.f};
    #pragma unroll
    for (int mi = 0; mi < 4; ++mi) {
        #pragma unroll
        for (int r = 0; r < 4; ++r) {
            const int lrow = wr * 64 + mi * 16 + quad * 4 + r;
            const int irow = row0 + lrow;
            float s = 0.f;
            #pragma unroll
            for (int ni = 0; ni < 4; ++ni) {
                const int jcol = col0 + wc * 64 + ni * 16 + cl;
                float e = __expf(TEMP_INV * acc[mi][ni][r]);
                e = (jcol <= irow) ? 0.f : e;
                s += e;
                colacc[ni] += e;
            }
            s += __shfl_xor(s, 1);
            s += __shfl_xor(s, 2);
            s += __shfl_xor(s, 4);
            s += __shfl_xor(s, 8);
            if (cl == 0) atomicAdd(&rsum[lrow], s);
        }
    }
    #pragma unroll
    for (int ni = 0; ni < 4; ++ni) {
        float c = colacc[ni];
        c += __shfl_xor(c, 16);
        c += __shfl_xor(c, 32);
        if (quad == 0) atomicAdd(&csum[wc * 64 + ni * 16 + cl], c);
    }
    __syncthreads();
    if (tid < 128) atomicAdd(&rowsum[row0 + tid], rsum[tid]);
    if (tid < 256) atomicAdd(&rowsum[col0 + tid], csum[tid]);

    // ---- fence-free finalize (v15 tree: 32 groups x 33) ----
    // __syncthreads drains vmcnt(0): rowsum atomics complete at coherence point
    // before the counter increments.
    __syncthreads();
    if (tid == 0) {
        lastf = 0;
        unsigned old = __hip_atomic_fetch_add(&ctl[(t0 & (NGRP - 1)) * 32], 1u,
                                              __ATOMIC_RELAXED,
                                              __HIP_MEMORY_SCOPE_AGENT);
        if (old == GRP_SZ - 1) {
            unsigned top = __hip_atomic_fetch_add(&ctl[1024], 1u,
                                                  __ATOMIC_RELAXED,
                                                  __HIP_MEMORY_SCOPE_AGENT);
            lastf = (top == NGRP - 1);
        }
    }
    __syncthreads();
    if (lastf) {
        float s = 0.f;
        for (int i = tid; i < N_TOT; i += 512)
            s += logf(atomicAdd(&rowsum[i], 0.0f));   // coherent RMW read
        float p = 0.f;
        for (int i = tid; i < B_ROWS; i += 512) p += pos[i];
        #pragma unroll
        for (int m = 32; m >= 1; m >>= 1) {
            s += __shfl_xor(s, m);
            p += __shfl_xor(p, m);
        }
        if (lane == 0) pw[wid] = s;
        __syncthreads();
        __shared__ float wp[8];
        if (lane == 0) wp[wid] = p;
        __syncthreads();
        if (tid == 0) {
            float tot = 0.f, ptot = 0.f;
            #pragma unroll
            for (int w = 0; w < 8; ++w) { tot += pw[w]; ptot += wp[w]; }
            // loss = mean(log denom) - (2*posSum)/(temp*N)
            out[0] = tot / (float)N_TOT - ptot * (2.0f * TEMP_INV / (float)N_TOT);
        }
    }
}

extern "C" void kernel_launch(void* const* d_in, const int* in_sizes, int n_in,
                              void* d_out, int out_size, void* d_ws, size_t ws_size,
                              hipStream_t stream) {
    const float* xi = (const float*)d_in[0];
    const float* xj = (const float*)d_in[1];
    float* out = (float*)d_out;
    char* ws = (char*)d_ws;

    unsigned short* z = (unsigned short*)ws;                       // 8 MB bf16
    float* rowsum = (float*)(ws + (size_t)N_TOT * D_DIM * 2);      // 32 KB
    float* pos = rowsum + N_TOT;                                   // 16 KB
    unsigned* ctl = (unsigned*)(pos + B_ROWS);                     // 8.6 KB

    normpos_kernel<<<B_ROWS / 4, 256, 0, stream>>>(xi, xj, z, pos, rowsum, ctl);
    simrow_kernel<<<NT, 512, 0, stream>>>(z, rowsum, pos, out, ctl);
}